// Round 2
// baseline (64697.223 us; speedup 1.0000x reference)
//
#include <hip/hip_runtime.h>

// Problem dims
#define Bdim 256
#define Sdim 512
#define Cdim 512
#define Hdim 512
#define NP 16      // batch pipelines (M=16 rows each)
#define NSLICE 16  // N-slice workgroups per pipeline

typedef __attribute__((ext_vector_type(8))) short bfrag;          // 8 bf16 MFMA A/B frag
typedef __attribute__((ext_vector_type(8))) unsigned short u16x8;
typedef __attribute__((ext_vector_type(4))) float f32x4;          // MFMA C/D frag
typedef unsigned long long u64;

__device__ __forceinline__ unsigned short f2bf_rne(float f) {
    union { float f; unsigned u; } v; v.f = f;
    return (unsigned short)((v.u + 0x7fffu + ((v.u >> 16) & 1u)) >> 16);
}
__device__ __forceinline__ float sigmoidf_(float x) { return 1.0f / (1.0f + __expf(-x)); }

// ---------------------------------------------------------------------------
// Pack a K x N fp32 weight into bf16 MFMA B-fragment layout:
//   dst[ (n16*(K/32) + kc)*512 + lane*8 + j ] = B[kc*32 + (lane>>4)*8 + j][n16*16 + (lane&15)]
// TRANS=false: src row-major (K,N). K is always 512 here.
template<bool TRANS>
__global__ __launch_bounds__(256) void pack_weight(const float* __restrict__ src,
                                                   unsigned short* __restrict__ dst,
                                                   int K, int N) {
    int tid = blockIdx.x * 256 + threadIdx.x;
    int total = (K >> 5) * (N >> 4) * 64;
    if (tid >= total) return;
    int lane = tid & 63;
    int blk  = tid >> 6;
    int kc   = blk & 15;
    int n16  = blk >> 4;
    int n  = (n16 << 4) + (lane & 15);
    int kb = (kc << 5) + ((lane >> 4) << 3);
    u16x8 v;
#pragma unroll
    for (int j = 0; j < 8; ++j) {
        int k = kb + j;
        float f = TRANS ? src[(size_t)n * K + k] : src[(size_t)k * N + n];
        v[j] = f2bf_rne(f);
    }
    *(u16x8*)(dst + ((size_t)tid << 3)) = v;
}

// ---------------------------------------------------------------------------
// Composed gate weights: C[k][n] = (Wadd ? Wadd[n][k] : 0) + sum_j A[j][k]*Whm[n][j]
__global__ __launch_bounds__(256) void weff_kernel(const float* __restrict__ A,
                                                   const float* __restrict__ Whm,
                                                   const float* __restrict__ Wadd,
                                                   float* __restrict__ C) {
    int n = blockIdx.x;                       // 0..2047
    int k = blockIdx.y * 256 + threadIdx.x;   // 0..511
    const float* wrow = Whm + (size_t)n * 512;
    float acc = 0.f;
#pragma unroll 8
    for (int j = 0; j < 512; ++j) acc += A[(size_t)j * 512 + k] * wrow[j];
    if (Wadd) acc += Wadd[(size_t)n * 512 + k];
    C[(size_t)k * 2048 + n] = acc;
}

// beff[n] = bih[n] + bhm[n] + sum_j (bmx[j]+bmh[j]) * Whm[n][j]
__global__ __launch_bounds__(256) void beff_kernel(const float* __restrict__ bmx,
                                                   const float* __restrict__ bmh,
                                                   const float* __restrict__ Whm,
                                                   const float* __restrict__ bih,
                                                   const float* __restrict__ bhm,
                                                   float* __restrict__ beff) {
    int n = blockIdx.x * 256 + threadIdx.x;
    const float* wrow = Whm + (size_t)n * 512;
    float acc = bih[n] + bhm[n];
#pragma unroll 8
    for (int j = 0; j < 512; ++j) acc += (bmx[j] + bmh[j]) * wrow[j];
    beff[n] = acc;
}

// Init the h0 comm buffer: payload 0, tag 0 (s0 at t=0 expects tag 0).
__global__ __launch_bounds__(256) void init_state(u64* __restrict__ Gc) {
    int tid = blockIdx.x * 256 + threadIdx.x;
    for (int i = tid; i < NP * 4096; i += gridDim.x * 256) Gc[i] = 0ull;
}

// ---------------------------------------------------------------------------
// Self-tagged communication: each 8B word = {lo: 2 x bf16 payload, hi: stage tag}.
// Producer stores words fire-and-forget (agent scope -> LIC). Consumer loads the
// word and the tag arrives atomically WITH the payload, so no drain, no flag,
// no fence. Tag = global stage counter q (6*t + stage), strictly increasing.
// Overwrite safety is transitive: a writer at stage q+2 only starts after
// observing all q+1 tags, which post-date all stage-q reads.
//
// Comm buffer layout per pipeline: word[m][kpair] , m in [0,16), kpair in [0,256):
//   payload = { vec[m][2*kpair], vec[m][2*kpair+1] }  (vec = 16x512 bf16 row-major)
// Consumer A-frag (lane l: row lm=l&15, k = kc*32 + lq*8 + j):
//   4 consecutive words at  lm*256 + kc*16 + lq*4.

// Burst-load all 16 k-chunks (4 words each) and spin (per-lane) until every
// word carries tag q. Respins reload ALL still-invalid chunks per sweep, so a
// straggler costs ~1 LIC RT, not 16 serial RTs.
__device__ __forceinline__ void validate16(u64 (*aw)[4], const u64* __restrict__ base,
                                           unsigned q) {
    unsigned inv = 0xFFFFu;
    while (inv) {
#pragma unroll
        for (int kc = 0; kc < 16; ++kc) {
            if (inv & (1u << kc)) {
#pragma unroll
                for (int wd = 0; wd < 4; ++wd)
                    aw[kc][wd] = __hip_atomic_load(base + kc * 16 + wd,
                                                   __ATOMIC_RELAXED, __HIP_MEMORY_SCOPE_AGENT);
            }
        }
        unsigned next = 0;
#pragma unroll
        for (int kc = 0; kc < 16; ++kc) {
            if (inv & (1u << kc)) {
                bool ok = (unsigned)(aw[kc][0] >> 32) == q && (unsigned)(aw[kc][1] >> 32) == q
                       && (unsigned)(aw[kc][2] >> 32) == q && (unsigned)(aw[kc][3] >> 32) == q;
                if (!ok) next |= 1u << kc;
            }
        }
        inv = next;
    }
}

// Pair lanes (n even / n odd) via shfl and emit one tagged 8B word.
__device__ __forceinline__ void store_tagged(u64* __restrict__ Dc, int m, int n,
                                             unsigned short b, unsigned q, int lane) {
    unsigned ub = b;
    unsigned pb = __shfl_xor(ub, 1);
    if (!(lane & 1)) {
        u64 word = (u64)(ub | (pb << 16)) | ((u64)q << 32);
        __hip_atomic_store(Dc + m * 256 + (n >> 1), word,
                           __ATOMIC_RELAXED, __HIP_MEMORY_SCOPE_AGENT);
    }
}

// One mogrifier stage for this WG's 32-column slice:
//   new = 2*sigmoid( (A @ W)[:, slice] ) * prev ; prev/new in registers,
//   result broadcast to the pipeline as tagged words.
__device__ __forceinline__ void mog_stage(const u64* __restrict__ Ac,
                                          const bfrag* __restrict__ B,
                                          u64* __restrict__ Dc,
                                          float pv[2][4],
                                          unsigned q_in, unsigned q_out,
                                          int s, int lane, int lm, int lq) {
    u64 aw[16][4];
    validate16(aw, Ac + lm * 256 + lq * 4, q_in);
    f32x4 acc[2] = {};
#pragma unroll
    for (int kc = 0; kc < 16; ++kc) {
        union { unsigned u[4]; bfrag f; } A;
#pragma unroll
        for (int wd = 0; wd < 4; ++wd) A.u[wd] = (unsigned)aw[kc][wd];
        acc[0] = __builtin_amdgcn_mfma_f32_16x16x32_bf16(A.f, B[kc * 64],        acc[0], 0, 0, 0);
        acc[1] = __builtin_amdgcn_mfma_f32_16x16x32_bf16(A.f, B[1024 + kc * 64], acc[1], 0, 0, 0);
    }
#pragma unroll
    for (int nt = 0; nt < 2; ++nt)
#pragma unroll
        for (int r = 0; r < 4; ++r) {
            int n = s * 32 + nt * 16 + lm;    // C/D: col=lane&15, row=(lane>>4)*4+r
            int m = lq * 4 + r;
            float v = 2.0f * sigmoidf_(acc[nt][r]) * pv[nt][r];
            pv[nt][r] = v;
            store_tagged(Dc, m, n, f2bf_rne(v), q_out, lane);
        }
}

// ---------------------------------------------------------------------------
// The whole S=512 recurrence in ONE kernel. Grid: 256 WGs x 64 thr.
// WG w: pipeline p = w>>4 (batch rows p*16..p*16+15), slice s = w&15
// (columns s*32..s*32+31). Stage cadence is set purely by tagged-word flight
// (~1 LIC RT) + consumer poll detect — no drains, no flag round trips.
__global__ __launch_bounds__(64, 1)
void moglstm_persistent(const float* __restrict__ x,
                        const unsigned short* __restrict__ Qp,
                        const unsigned short* __restrict__ Rp,
                        const unsigned short* __restrict__ WXp,
                        const unsigned short* __restrict__ WHp,
                        const float* __restrict__ beff,
                        u64* __restrict__ Xcb,
                        u64* __restrict__ Mcb,
                        u64* __restrict__ Gcb,
                        float* __restrict__ out) {
    const int w = blockIdx.x;
    const int p = w >> 4, s = w & 15;
    const int lane = threadIdx.x & 63, lm = lane & 15, lq = lane >> 4;
    u64* Xc = Xcb + p * 4096;   // x-vector comm (tagged)
    u64* Mc = Mcb + p * 4096;   // h1/h2 comm
    u64* Gc = Gcb + p * 4096;   // cell-output h comm (h0 for next t)

    const bfrag* BQ = (const bfrag*)Qp + (size_t)s * 2048 + lane;
    const bfrag* BR = (const bfrag*)Rp + (size_t)s * 2048 + lane;

    float px[2][4];                 // this WG's x slice (fp32 master)
    float ph[2][4] = {};            // this WG's h slice
    float cst[2][4] = {};           // cell state slice — registers only
    float bia[4][2];
#pragma unroll
    for (int g = 0; g < 4; ++g)
#pragma unroll
        for (int nt = 0; nt < 2; ++nt)
            bia[g][nt] = beff[g * 512 + s * 32 + nt * 16 + lm];

    const size_t xbase = (size_t)(p * 16) * Sdim * Cdim;
    const size_t obase = (size_t)(p * 16) * Sdim * Hdim;

#pragma unroll 1
    for (int t = 0; t < Sdim; ++t) {
        const unsigned q0 = 6u * (unsigned)t;
        // Preload x_t elementwise BEFORE any polling (independent of tags).
#pragma unroll
        for (int nt = 0; nt < 2; ++nt)
#pragma unroll
            for (int r = 0; r < 4; ++r) {
                int n = s * 32 + nt * 16 + lm;
                int m = lq * 4 + r;
                px[nt][r] = x[xbase + (size_t)m * (Sdim * Cdim) + (size_t)t * Cdim + n];
            }
        // s0: x1 = 2σ(h0@Q)·x_t   (reads Gc@q0, writes Xc@q0+1)
        mog_stage(Gc, BQ, Xc, px, q0,     q0 + 1, s, lane, lm, lq);
        // s1: h1 = 2σ(x1@R)·h0    (reads Xc@q0+1, writes Mc@q0+2)
        mog_stage(Xc, BR, Mc, ph, q0 + 1, q0 + 2, s, lane, lm, lq);
        // s2: x2 = 2σ(h1@Q)·x1
        mog_stage(Mc, BQ, Xc, px, q0 + 2, q0 + 3, s, lane, lm, lq);
        // s3: h2 = 2σ(x2@R)·h1
        mog_stage(Xc, BR, Mc, ph, q0 + 3, q0 + 4, s, lane, lm, lq);
        // s4: x3 = 2σ(h2@Q)·x2
        mog_stage(Mc, BQ, Xc, px, q0 + 4, q0 + 5, s, lane, lm, lq);
        // s5: gates = x3@Weff_x + h2@Weff_h + beff ; fused LSTM cell.
        {
            f32x4 acc[4][2] = {};
            u64 aw[16][4];
            // X contribution
            validate16(aw, Xc + lm * 256 + lq * 4, q0 + 5);
#pragma unroll
            for (int kc = 0; kc < 16; ++kc) {
                union { unsigned u[4]; bfrag f; } A;
#pragma unroll
                for (int wd = 0; wd < 4; ++wd) A.u[wd] = (unsigned)aw[kc][wd];
#pragma unroll
                for (int g = 0; g < 4; ++g) {
                    const bfrag* BX = (const bfrag*)WXp + ((size_t)((g * 32 + s * 2) * 16 + kc)) * 64 + lane;
                    acc[g][0] = __builtin_amdgcn_mfma_f32_16x16x32_bf16(A.f, BX[0],    acc[g][0], 0, 0, 0);
                    acc[g][1] = __builtin_amdgcn_mfma_f32_16x16x32_bf16(A.f, BX[1024], acc[g][1], 0, 0, 0);
                }
            }
            // H contribution (older tag — guaranteed ready by now, cheap revalidate)
            validate16(aw, Mc + lm * 256 + lq * 4, q0 + 4);
#pragma unroll
            for (int kc = 0; kc < 16; ++kc) {
                union { unsigned u[4]; bfrag f; } A;
#pragma unroll
                for (int wd = 0; wd < 4; ++wd) A.u[wd] = (unsigned)aw[kc][wd];
#pragma unroll
                for (int g = 0; g < 4; ++g) {
                    const bfrag* BH = (const bfrag*)WHp + ((size_t)((g * 32 + s * 2) * 16 + kc)) * 64 + lane;
                    acc[g][0] = __builtin_amdgcn_mfma_f32_16x16x32_bf16(A.f, BH[0],    acc[g][0], 0, 0, 0);
                    acc[g][1] = __builtin_amdgcn_mfma_f32_16x16x32_bf16(A.f, BH[1024], acc[g][1], 0, 0, 0);
                }
            }
            // fused cell update
#pragma unroll
            for (int nt = 0; nt < 2; ++nt)
#pragma unroll
                for (int r = 0; r < 4; ++r) {
                    int n = s * 32 + nt * 16 + lm;
                    int m = lq * 4 + r;
                    float ig = sigmoidf_(acc[0][nt][r] + bia[0][nt]);
                    float fg = sigmoidf_(acc[1][nt][r] + bia[1][nt]);
                    float gg = tanhf(acc[2][nt][r] + bia[2][nt]);
                    float og = sigmoidf_(acc[3][nt][r] + bia[3][nt]);
                    float c = fg * cst[nt][r] + ig * gg;
                    cst[nt][r] = c;
                    float h = og * tanhf(c);
                    ph[nt][r] = h;                                   // own h0 slice for next t
                    store_tagged(Gc, m, n, f2bf_rne(h), q0 + 6, lane); // h0 for all slices
                    out[obase + (size_t)m * (Sdim * Hdim) + (size_t)t * Hdim + n] = h;
                }
        }
    }
}

// ---------------------------------------------------------------------------
extern "C" void kernel_launch(void* const* d_in, const int* in_sizes, int n_in,
                              void* d_out, int out_size, void* d_ws, size_t ws_size,
                              hipStream_t stream) {
    const float* x     = (const float*)d_in[0];
    const float* Wih_w = (const float*)d_in[1];
    const float* Wih_b = (const float*)d_in[2];
    const float* Wmx_w = (const float*)d_in[3];
    const float* Wmx_b = (const float*)d_in[4];
    const float* Wmh_w = (const float*)d_in[5];
    const float* Wmh_b = (const float*)d_in[6];
    const float* Whm_w = (const float*)d_in[7];
    const float* Whm_b = (const float*)d_in[8];
    const float* Q     = (const float*)d_in[9];
    const float* R     = (const float*)d_in[10];
    float* out = (float*)d_out;

    // workspace layout (~10.5 MB)
    unsigned short* packQ  = (unsigned short*)d_ws;
    unsigned short* packR  = packQ  + 512 * 512;
    unsigned short* packWX = packR  + 512 * 512;    // Weff_x packed (512 x 2048)
    unsigned short* packWH = packWX + 512 * 2048;   // Weff_h packed
    u64* Xcb = (u64*)(packWH + 512 * 2048);         // NP * 4096 tagged words each
    u64* Mcb = Xcb + NP * 4096;
    u64* Gcb = Mcb + NP * 4096;
    float* beff    = (float*)(Gcb + NP * 4096);     // 2048
    float* scratch = beff + 2048;                   // 512*2048 fp32 (setup only)

    pack_weight<false><<<dim3(128), dim3(256), 0, stream>>>(Q, packQ, 512, 512);
    pack_weight<false><<<dim3(128), dim3(256), 0, stream>>>(R, packR, 512, 512);
    // Weff_x = Wih^T + Wmx^T @ Whm^T  (fp32, then pack to bf16 frag layout)
    weff_kernel<<<dim3(2048, 2), dim3(256), 0, stream>>>(Wmx_w, Whm_w, Wih_w, scratch);
    pack_weight<false><<<dim3(512), dim3(256), 0, stream>>>(scratch, packWX, 512, 2048);
    // Weff_h = Wmh^T @ Whm^T
    weff_kernel<<<dim3(2048, 2), dim3(256), 0, stream>>>(Wmh_w, Whm_w, nullptr, scratch);
    pack_weight<false><<<dim3(512), dim3(256), 0, stream>>>(scratch, packWH, 512, 2048);
    beff_kernel<<<dim3(8), dim3(256), 0, stream>>>(Wmx_b, Wmh_b, Whm_w, Wih_b, Whm_b, beff);
    init_state<<<dim3(64), dim3(256), 0, stream>>>(Gcb);

    moglstm_persistent<<<dim3(NP * NSLICE), dim3(64), 0, stream>>>(
        x, packQ, packR, packWX, packWH, beff, Xcb, Mcb, Gcb, out);
}